// Round 1
// baseline (128.962 us; speedup 1.0000x reference)
//
#include <hip/hip_runtime.h>
#include <hip/hip_bf16.h>

// Self_Attn_3D: B=8, H=W=64 (N=4096 tokens), C_IN=256, C_QK=32.
// out[b,n] = gamma * sum_m softmax(q_n.k_m) * vbar[b,m] + xbar[b,n]
//   vbar = x @ mean_j(Wv) + mean(bv);  xbar = mean_c(x)
// (channel-mean commutes through attention output -> scalar-V flash attention)
//
// R3: flash was est. latency/issue-bound at 2 waves/SIMD (grid 512) with
// ~44 scalar VALU per 64-score iter around the irreducible exp stream.
// Changes: (a) K-split x2 -> grid 1024, __launch_bounds__(256,4) for
// 4 waves/SIMD; partial (sum_p, sum_pv) per row combined by a 128-block
// epilogue kernel (static -88 bias => partials add exactly, no atomics).
// (b) packed-f32 (v_pk_add/v_pk_fma) accumulation: ~16 pk-VALU per iter.

typedef _Float16 half8  __attribute__((ext_vector_type(8)));
typedef _Float16 half4v __attribute__((ext_vector_type(4)));
typedef float    f32x4  __attribute__((ext_vector_type(4)));
typedef float    f32x2  __attribute__((ext_vector_type(2)));

#define LOG2E 1.4426950408889634f

#if __has_builtin(__builtin_amdgcn_exp2f)
#define EXP2(x) __builtin_amdgcn_exp2f(x)
#else
#define EXP2(x) exp2f(x)
#endif

// ---------------------------------------------------------------------------
// prep: build (a) Wfr = [Wq|Wk] as f16 in MFMA-B-fragment order
//             Wfr[((ch*4+quad)*64 + col)*8 + j] = W[c=ch*32+quad*8+j][col]
//       (b) wvbar[256] = row-mean of Wv, (c) bvbar = mean(bv)
// grid 129 x 256
// ---------------------------------------------------------------------------
__global__ __launch_bounds__(256) void prep_kernel(
    const float* __restrict__ Wq, const float* __restrict__ Wk,
    const float* __restrict__ Wv, const float* __restrict__ bv,
    _Float16* __restrict__ Wfr, float* __restrict__ wvbar, float* __restrict__ bvbar)
{
  int bid = blockIdx.x, tid = threadIdx.x;
  if (bid < 64) {
    int col = bid, c = tid;
    float v = (col < 32) ? Wq[c * 32 + col] : Wk[c * 32 + (col - 32)];
    int ch = c >> 5, quad = (c >> 3) & 3, j = c & 7;
    Wfr[(size_t)((ch * 4 + quad) * 64 + col) * 8 + j] = (_Float16)v;
  } else if (bid < 128) {
    // one wave per Wv row: row-mean over 256 cols
    int row = (bid - 64) * 4 + (tid >> 6);
    int lane = tid & 63;
    const float* p = Wv + (size_t)row * 256 + lane * 4;
    float s = p[0] + p[1] + p[2] + p[3];
    #pragma unroll
    for (int off = 32; off >= 1; off >>= 1) s += __shfl_xor(s, off);
    if (lane == 0) wvbar[row] = s * (1.0f / 256.0f);
  } else {
    if (tid < 64) {
      const float* p = bv + tid * 4;
      float s = p[0] + p[1] + p[2] + p[3];
      #pragma unroll
      for (int off = 32; off >= 1; off >>= 1) s += __shfl_xor(s, off);
      if (tid == 0) bvbar[0] = s * (1.0f / 256.0f);
    }
  }
}

// ---------------------------------------------------------------------------
// proj: per 64-token tile: Qh=(x@Wq+bq)*log2e (f16), Kh=x@Wk+bk (f16),
//       vbar, xbar (f32). MFMA f16 16x16x32, A from LDS, B direct from Wfr.
// grid 512 x 256
// ---------------------------------------------------------------------------
__global__ __launch_bounds__(256) void proj_kernel(
    const float* __restrict__ x, const _Float16* __restrict__ Wfr,
    const float* __restrict__ bq, const float* __restrict__ bk,
    const float* __restrict__ wvbar, const float* __restrict__ bvbar,
    _Float16* __restrict__ Qh, _Float16* __restrict__ Kh,
    float* __restrict__ vbarO, float* __restrict__ xbarO)
{
  __shared__ _Float16 XT[64 * 264];   // 64 tokens x 256 f16, stride 264 (bank spread)
  int tid = threadIdx.x, blk = blockIdx.x;
  size_t tok0 = (size_t)blk * 64;

  // stage x -> XT (f32->f16), fully coalesced global reads
  const float4* xg4 = (const float4*)x;
  #pragma unroll
  for (int i = 0; i < 16; ++i) {
    int f = i * 256 + tid;            // 0..4095 float4s in this tile
    int tok = f >> 6, c4 = f & 63;
    float4 v = xg4[(size_t)blk * 4096 + f];
    half4v h;
    h.x = (_Float16)v.x; h.y = (_Float16)v.y; h.z = (_Float16)v.z; h.w = (_Float16)v.w;
    *(half4v*)&XT[tok * 264 + c4 * 4] = h;
  }
  __syncthreads();

  // vbar / xbar: one thread per token (f16-rounded x is fine: error ~1e-5)
  if (tid < 64) {
    float vs = 0.f, xs = 0.f;
    #pragma unroll 4
    for (int g = 0; g < 32; ++g) {
      half8 h = *(const half8*)&XT[tid * 264 + g * 8];
      #pragma unroll
      for (int j = 0; j < 8; ++j) {
        float xv = (float)h[j];
        vs += xv * wvbar[g * 8 + j];   // uniform -> s_load
        xs += xv;
      }
    }
    vbarO[tok0 + tid] = vs + bvbar[0];
    xbarO[tok0 + tid] = xs * (1.0f / 256.0f);
  }

  // MFMA: 64 tokens x 64 outputs, K=256 in 8 chunks of 32
  int lane = tid & 63, w = tid >> 6;
  int l15 = lane & 15, quad = lane >> 4;
  f32x4 acc[4] = {(f32x4){0,0,0,0},(f32x4){0,0,0,0},(f32x4){0,0,0,0},(f32x4){0,0,0,0}};
  #pragma unroll
  for (int ch = 0; ch < 8; ++ch) {
    half8 a = *(const half8*)&XT[(w * 16 + l15) * 264 + ch * 32 + quad * 8];
    #pragma unroll
    for (int ct = 0; ct < 4; ++ct) {
      half8 bf = *(const half8*)(Wfr + (size_t)((ch * 4 + quad) * 64 + ct * 16 + l15) * 8);
      acc[ct] = __builtin_amdgcn_mfma_f32_16x16x32_f16(a, bf, acc[ct], 0, 0, 0);
    }
  }
  // epilogue: D layout col=lane&15, row=quad*4+reg
  #pragma unroll
  for (int ct = 0; ct < 4; ++ct) {
    int col = ct * 16 + l15;
    #pragma unroll
    for (int r = 0; r < 4; ++r) {
      int token = w * 16 + quad * 4 + r;
      if (ct < 2) {
        float val = (acc[ct][r] + bq[col]) * LOG2E;      // fold log2e into Q
        Qh[(tok0 + token) * 32 + col] = (_Float16)val;
      } else {
        float val = acc[ct][r] + bk[col - 32];
        Kh[(tok0 + token) * 32 + (col - 32)] = (_Float16)val;
      }
    }
  }
}

// ---------------------------------------------------------------------------
// flash v3: scalar-V attention, barrier-free, K-split x2. One block = 64
// Q-rows x one K-half (2048 keys) of one batch; 4 waves x 16 rows. K
// B-fragments read DIRECTLY from global (layout matches MFMA B operand;
// 1 KB coalesced per load, L2-hot). Static-max softmax: s = q.k*log2e - 88
// via MFMA C bias; p = 2^s. Partials (sum_p, sum_p*v) per row -> combine.
// grid 1024 x 256, 4 waves/SIMD
// ---------------------------------------------------------------------------
__global__ __launch_bounds__(256, 4) void flash_kernel(
    const _Float16* __restrict__ Qh, const _Float16* __restrict__ Kh,
    const float* __restrict__ vbar,
    float* __restrict__ lpart, float* __restrict__ opart)
{
  int tid = threadIdx.x, blk = blockIdx.x;
  int b = blk >> 7;                 // 128 blocks per batch
  int qt = (blk >> 1) & 63;         // Q tile (64 rows)
  int ks = blk & 1;                 // K half
  int lane = tid & 63, w = tid >> 6;
  int l15 = lane & 15, quad = lane >> 4;

  const _Float16* Qb = Qh + (size_t)b * 4096 * 32;
  const _Float16* Kb = Kh + (size_t)b * 4096 * 32;
  const float* vb = vbar + (size_t)b * 4096;

  // per-wave Q fragment: A[m=lane&15][k=quad*8+j]
  int qrow = qt * 64 + w * 16 + l15;
  half8 aq = *(const half8*)(Qb + (size_t)qrow * 32 + quad * 8);

  f32x2 l2[4], o2[4];
  #pragma unroll
  for (int r = 0; r < 4; ++r) { l2[r] = (f32x2){0, 0}; o2[r] = (f32x2){0, 0}; }
  const f32x4 cinit = {-88.f, -88.f, -88.f, -88.f};

  // B-fragment address for this lane: K row (ks*2048 + ct*16+l15), halves quad*8..+7
  const _Float16* kfrag = Kb + ((size_t)ks * 2048 + l15) * 32 + quad * 8;
  const float* vfrag = vb + ks * 2048 + l15;

  #pragma unroll 2
  for (int kt = 0; kt < 32; ++kt) {
    half8 bk8[4];
    float vbl[4];
    #pragma unroll
    for (int ct = 0; ct < 4; ++ct) {
      bk8[ct] = *(const half8*)(kfrag + (size_t)(kt * 64 + ct * 16) * 32);
      vbl[ct] = vfrag[kt * 64 + ct * 16];
    }
    f32x4 sc[4];
    #pragma unroll
    for (int ct = 0; ct < 4; ++ct)
      sc[ct] = __builtin_amdgcn_mfma_f32_16x16x32_f16(aq, bk8[ct], cinit, 0, 0, 0);
    f32x2 vA = {vbl[0], vbl[1]}, vB = {vbl[2], vbl[3]};
    #pragma unroll
    for (int r = 0; r < 4; ++r) {   // rows quad*4+r; cols ct*16+(lane&15)
      float p0 = EXP2(sc[0][r]), p1 = EXP2(sc[1][r]);
      float p2 = EXP2(sc[2][r]), p3 = EXP2(sc[3][r]);
      f32x2 pA = {p0, p1}, pB = {p2, p3};
      l2[r] += pA + pB;             // 2x v_pk_add_f32
      o2[r] += pA * vA;             // v_pk_fma_f32 (ffp-contract)
      o2[r] += pB * vB;             // v_pk_fma_f32
    }
  }

  float lacc[4], oacc[4];
  #pragma unroll
  for (int r = 0; r < 4; ++r) { lacc[r] = l2[r].x + l2[r].y; oacc[r] = o2[r].x + o2[r].y; }

  // reduce partials across the 16 lanes sharing a quad
  #pragma unroll
  for (int r = 0; r < 4; ++r) {
    #pragma unroll
    for (int off = 1; off < 16; off <<= 1) {
      lacc[r] += __shfl_xor(lacc[r], off);
      oacc[r] += __shfl_xor(oacc[r], off);
    }
  }
  if (l15 == 0) {
    #pragma unroll
    for (int r = 0; r < 4; ++r) {
      int row = qt * 64 + w * 16 + quad * 4 + r;
      size_t g = (size_t)b * 4096 + row;
      lpart[(size_t)ks * 32768 + g] = lacc[r];
      opart[(size_t)ks * 32768 + g] = oacc[r];
    }
  }
}

// ---------------------------------------------------------------------------
// combine: out = gamma * (sum_ks o) / (sum_ks l) + xbar.  grid 128 x 256
// ---------------------------------------------------------------------------
__global__ __launch_bounds__(256) void combine_kernel(
    const float* __restrict__ lpart, const float* __restrict__ opart,
    const float* __restrict__ xbar, const float* __restrict__ gamma,
    float* __restrict__ out)
{
  int i = blockIdx.x * 256 + threadIdx.x;      // 0..32767
  float l = lpart[i] + lpart[32768 + i];
  float o = opart[i] + opart[32768 + i];
  out[i] = gamma[0] * (o / l) + xbar[i];
}

// ---------------------------------------------------------------------------
extern "C" void kernel_launch(void* const* d_in, const int* in_sizes, int n_in,
                              void* d_out, int out_size, void* d_ws, size_t ws_size,
                              hipStream_t stream)
{
  const float* x     = (const float*)d_in[0];
  const float* Wq    = (const float*)d_in[1];
  const float* bq    = (const float*)d_in[2];
  const float* Wk    = (const float*)d_in[3];
  const float* bk    = (const float*)d_in[4];
  const float* Wv    = (const float*)d_in[5];
  const float* bv    = (const float*)d_in[6];
  const float* gamma = (const float*)d_in[7];
  float* out = (float*)d_out;

  char* ws = (char*)d_ws;                          // needs ~5.1 MB
  _Float16* Wfr  = (_Float16*)(ws);                // 32 KB
  float* wvbar   = (float*)(ws + 32768);           // 1 KB
  float* bvbar   = (float*)(ws + 33792);           // 4 B
  _Float16* Qh   = (_Float16*)(ws + 65536);        // 2 MB
  _Float16* Kh   = (_Float16*)(ws + 65536 + 2097152);        // 2 MB
  float* vbarA   = (float*)(ws + 65536 + 4194304);           // 128 KB
  float* xbarA   = (float*)(ws + 65536 + 4194304 + 131072);  // 128 KB
  float* lpart   = (float*)(ws + 65536 + 4194304 + 262144);  // 256 KB (2 x 32768)
  float* opart   = (float*)(ws + 65536 + 4194304 + 524288);  // 256 KB (2 x 32768)

  prep_kernel<<<129, 256, 0, stream>>>(Wq, Wk, Wv, bv, Wfr, wvbar, bvbar);
  proj_kernel<<<512, 256, 0, stream>>>(x, Wfr, bq, bk, wvbar, bvbar, Qh, Kh, vbarA, xbarA);
  flash_kernel<<<1024, 256, 0, stream>>>(Qh, Kh, vbarA, lpart, opart);
  combine_kernel<<<128, 256, 0, stream>>>(lpart, opart, xbarA, gamma, out);
}